// Round 7
// baseline (236.895 us; speedup 1.0000x reference)
//
#include <hip/hip_runtime.h>
#include <hip/hip_fp16.h>
#include <math.h>

#define NPTS 1024
#define DIM  128
#define BATCH 16
#define NCLOUD 32
#define BIGF 3.0e38f
#define BMAX 0xFFFFFFFFFFFFFFFFull

// ws layout (fast path):
//   [0, 64)       : double mse_sum
//   DEATHS_OFF    : float deaths[32][1024] (appended, then sorted in place)
//   D_OFF  +64MB  : fp16 D[32][1024][1024]
//   XBF_OFF +8MB  : bf16 x[32][1024][128]
//   SQ_OFF +128KB : f32 sq[32][1024]
//   COMP_OFF      : u32 comp[32][1024]
//   BEST_OFF      : u64 best[32][1024]
//   CNT_OFF       : u32 ncomp[32], u32 dcnt[32]
//   BAR_OFF       : u32 bar[32], u32 gen[32]
#define DEATHS_OFF 64
#define D_OFF 196608
#define XBF_OFF ((size_t)D_OFF + (size_t)NCLOUD * NPTS * NPTS * 2)
#define SQ_OFF   (XBF_OFF + (size_t)NCLOUD * NPTS * DIM * 2)
#define COMP_OFF (SQ_OFF + (size_t)NCLOUD * NPTS * 4)
#define BEST_OFF (COMP_OFF + (size_t)NCLOUD * NPTS * 4)
#define CNT_OFF  (BEST_OFF + (size_t)NCLOUD * NPTS * 8)
#define BAR_OFF  (CNT_OFF + 256)
#define WS_NEED  (BAR_OFF + 256)

typedef __attribute__((ext_vector_type(8))) short short8;
typedef __attribute__((ext_vector_type(4))) float f32x4;

__device__ __forceinline__ unsigned umin32(unsigned a, unsigned b) { return a < b ? a : b; }

__device__ __forceinline__ unsigned bfbits(float f) {
  unsigned u = __float_as_uint(f);
  return (u + 0x7FFFu + ((u >> 16) & 1u)) >> 16;  // RNE, finite inputs
}

// ---------------- fused prep + MSE + state init ----------------
__global__ __launch_bounds__(256) void prep_mse(const float* __restrict__ x1,
                                                const float* __restrict__ x2,
                                                unsigned short* __restrict__ xbf,
                                                float* __restrict__ sqg,
                                                unsigned* __restrict__ comp,
                                                unsigned long long* __restrict__ best,
                                                unsigned* __restrict__ ncomp,
                                                unsigned* __restrict__ dcnt,
                                                float* __restrict__ deaths,
                                                unsigned* __restrict__ barg,
                                                double* __restrict__ acc) {
  const int b = blockIdx.x;
  const int s = blockIdx.y;
  const int tid = threadIdx.x;

  if (s == 0 && tid == 0) {
    ncomp[b] = NPTS; ncomp[16 + b] = NPTS;
    dcnt[b] = 0; dcnt[16 + b] = 0;
    deaths[(size_t)b * NPTS + NPTS - 1] = BIGF;
    deaths[(size_t)(16 + b) * NPTS + NPTS - 1] = BIGF;
  }
  if (b == 0 && s == 0 && tid < 64) barg[tid] = 0;  // bar[32] + gen[32]

  const int half = tid >> 7;
  const int r = s * 128 + (tid & 127);
  const int cloud = half * 16 + b;
  const float* xc = (half ? x2 : x1) + (size_t)b * NPTS * DIM;
  const float4* xr = (const float4*)(xc + (size_t)r * DIM);
  const float4* yr = (const float4*)(x2 + (size_t)b * NPTS * DIM + (size_t)r * DIM);
  uint4* orow = (uint4*)xbf + (size_t)cloud * NPTS * (DIM / 8) + (size_t)r * (DIM / 8);

  float mse_s = 0.f;
  float ax = 0.f, ay = 0.f, az = 0.f, aw = 0.f;
  #pragma unroll 4
  for (int m = 0; m < 32; m += 2) {
    float4 v0 = xr[m], v1 = xr[m + 1];
    ax = fmaf(v0.x, v0.x, ax); ay = fmaf(v0.y, v0.y, ay);
    az = fmaf(v0.z, v0.z, az); aw = fmaf(v0.w, v0.w, aw);
    ax = fmaf(v1.x, v1.x, ax); ay = fmaf(v1.y, v1.y, ay);
    az = fmaf(v1.z, v1.z, az); aw = fmaf(v1.w, v1.w, aw);
    uint4 o;
    o.x = bfbits(v0.x) | (bfbits(v0.y) << 16);
    o.y = bfbits(v0.z) | (bfbits(v0.w) << 16);
    o.z = bfbits(v1.x) | (bfbits(v1.y) << 16);
    o.w = bfbits(v1.z) | (bfbits(v1.w) << 16);
    orow[m >> 1] = o;
    if (half == 0) {
      float4 u0 = yr[m], u1 = yr[m + 1];
      float d0 = v0.x - u0.x, d1 = v0.y - u0.y, d2 = v0.z - u0.z, d3 = v0.w - u0.w;
      float e0 = v1.x - u1.x, e1 = v1.y - u1.y, e2 = v1.z - u1.z, e3 = v1.w - u1.w;
      mse_s += d0 * d0 + d1 * d1 + d2 * d2 + d3 * d3;
      mse_s += e0 * e0 + e1 * e1 + e2 * e2 + e3 * e3;
    }
  }
  sqg[cloud * NPTS + r] = (ax + ay) + (az + aw);
  comp[cloud * NPTS + r] = (unsigned)r;
  best[cloud * NPTS + r] = BMAX;

  #pragma unroll
  for (int off = 32; off; off >>= 1) mse_s += __shfl_xor(mse_s, off);
  __shared__ float wsum[4];
  int lane = tid & 63, wid = tid >> 6;
  if (lane == 0) wsum[wid] = mse_s;
  __syncthreads();
  if (tid == 0)
    atomicAdd(acc, (double)(wsum[0] + wsum[1] + wsum[2] + wsum[3]));
}

// ---------------- MFMA distance matrix (round-5 structure) + fused round-1 best ----
// 64x64 tile per block (4 waves), 33 KB LDS, row-major 2B stores (proven 44 us).
__global__ __launch_bounds__(256) void distmat_mfma(const unsigned short* __restrict__ xbf,
                                                    const float* __restrict__ sqg,
                                                    unsigned short* __restrict__ Dmat,
                                                    unsigned long long* __restrict__ best) {
  const int cloud = blockIdx.z;
  const int i0 = blockIdx.y * 64;
  const int j0 = blockIdx.x * 64;
  const int tid = threadIdx.x;
  const int lane = tid & 63, w = tid >> 6;
  const int l15 = lane & 15, kq = lane >> 4;

  __shared__ unsigned short Ash[64 * 128];
  __shared__ unsigned short Bsh[64 * 128];
  __shared__ float sqi_sh[64], sqj_sh[64];

  const uint4* xg = (const uint4*)xbf + (size_t)cloud * NPTS * (DIM / 8);
  uint4* A4 = (uint4*)Ash;
  uint4* B4 = (uint4*)Bsh;

  #pragma unroll
  for (int c = tid; c < 1024; c += 256) {
    int row = c >> 4, c16 = c & 15;
    int sidx = (row << 4) | (c16 ^ (row & 7));
    A4[sidx] = xg[((size_t)(i0 + row) << 4) | c16];
    B4[sidx] = xg[((size_t)(j0 + row) << 4) | c16];
  }
  if (tid < 64) sqi_sh[tid] = sqg[(size_t)cloud * NPTS + i0 + tid];
  else if (tid < 128) sqj_sh[tid - 64] = sqg[(size_t)cloud * NPTS + j0 + tid - 64];
  __syncthreads();

  const int ar = w * 16 + l15;
  f32x4 acc[4];
  #pragma unroll
  for (int jt = 0; jt < 4; ++jt) acc[jt] = (f32x4){0.f, 0.f, 0.f, 0.f};

  #pragma unroll
  for (int kk = 0; kk < 4; ++kk) {
    int acol = (kk * 4 + kq) ^ (ar & 7);
    short8 a = *(const short8*)&A4[(ar << 4) | acol];
    #pragma unroll
    for (int jt = 0; jt < 4; ++jt) {
      int br = jt * 16 + l15;
      int bcol = (kk * 4 + kq) ^ (br & 7);
      short8 bf = *(const short8*)&B4[(br << 4) | bcol];
      acc[jt] = __builtin_amdgcn_mfma_f32_16x16x32_bf16(a, bf, acc[jt], 0, 0, 0);
    }
  }

  unsigned short* Dc = Dmat + ((size_t)cloud << 20);
  unsigned long long* bestc = best + cloud * NPTS;

  unsigned kmin[4] = {0xFFFFFFFFu, 0xFFFFFFFFu, 0xFFFFFFFFu, 0xFFFFFFFFu};

  #pragma unroll
  for (int jt = 0; jt < 4; ++jt) {
    int jl = jt * 16 + l15;
    int gj = j0 + jl;
    float sqj = sqj_sh[jl];
    #pragma unroll
    for (int r = 0; r < 4; ++r) {
      int il = w * 16 + kq * 4 + r;
      int gi = i0 + il;
      float d2 = sqi_sh[il] + sqj - 2.f * acc[jt][r];
      float d = sqrtf(fmaxf(d2, 0.f) + 1e-12f);
      unsigned h = (gi == gj) ? 0x7C00u : (unsigned)__half_as_ushort(__float2half(d));
      Dc[(size_t)gi * NPTS + gj] = (unsigned short)h;
      kmin[r] = umin32(kmin[r], (h << 16) | (unsigned)gj);
    }
  }

  // fused Boruvka round-1: row min over this block's 64 cols, atomicMin per row
  #pragma unroll
  for (int r = 0; r < 4; ++r) {
    unsigned k = kmin[r];
    k = umin32(k, __shfl_xor(k, 1));
    k = umin32(k, __shfl_xor(k, 2));
    k = umin32(k, __shfl_xor(k, 4));
    k = umin32(k, __shfl_xor(k, 8));
    if (l15 == 0) {
      unsigned gi = (unsigned)(i0 + w * 16 + kq * 4 + r);
      unsigned j = k & 0xFFFFu, hv = k >> 16;
      unsigned cmn = umin32(gi, j);
      unsigned cmx = gi + j - cmn;
      unsigned long long k64 =
          ((unsigned long long)hv << 20) | (unsigned long long)((cmn << 10) | cmx);
      atomicMin(&bestc[gi], k64);
    }
  }
}

// ---------------- persistent Boruvka: all rounds in one launch ----------------
// grid (8, NCLOUD) x 256 thr, 1 block/CU -> co-resident. Per-cloud monotonic
// ticket barrier; cross-block state (comp/best/ncomp/gen) via device atomics
// only (per-XCD L2s are not coherent). Round 0 = merge of distmat-fused best.
__global__ __launch_bounds__(256) void boruvka_persist(const unsigned short* __restrict__ Dmat,
                                                       unsigned* __restrict__ comp,
                                                       unsigned long long* __restrict__ best,
                                                       unsigned* __restrict__ ncomp,
                                                       unsigned* __restrict__ dcnt,
                                                       float* __restrict__ deaths,
                                                       unsigned* __restrict__ bar,
                                                       unsigned* __restrict__ gen) {
  const int cloud = blockIdx.y;
  const int bx = blockIdx.x;
  const int tid = threadIdx.x;
  const int lane = tid & 63, wid = tid >> 6;
  unsigned* compc = comp + cloud * NPTS;
  unsigned long long* bestc = best + cloud * NPTS;
  const uint4* p = (const uint4*)(Dmat + ((size_t)cloud << 20));
  const unsigned jb0 = (unsigned)(lane << 3), jb1 = 512u + jb0;

  __shared__ unsigned short comp16[NPTS];
  __shared__ unsigned short par[NPTS];
  __shared__ unsigned lastFlag, cnt_sh, exit_sh;

  for (unsigned rnd = 0; rnd < 11; ++rnd) {
    // coherent reload of comp
    for (int i = tid; i < NPTS; i += 256)
      comp16[i] = (unsigned short)atomicAdd(&compc[i], 0u);
    __syncthreads();

    if (rnd > 0) {
      // ---- scan ----
      unsigned cj[16];
      #pragma unroll
      for (int e = 0; e < 8; ++e) cj[e] = comp16[(lane << 3) + e];
      #pragma unroll
      for (int e = 0; e < 8; ++e) cj[8 + e] = comp16[512 + (lane << 3) + e];

      const int row0 = bx * 128 + wid * 32;
      for (int rr = 0; rr < 32; ++rr) {
        int row = row0 + rr;
        unsigned ci = (unsigned)comp16[row];
        uint4 ra = p[row * 128 + lane];
        uint4 rb = p[row * 128 + 64 + lane];
        unsigned key = 0xFFFFFFFFu;
        #define ENT(word, cl, ch, jb) { \
          unsigned klo = ((word) << 16) | (jb); \
          unsigned khi = ((word) & 0xFFFF0000u) | ((jb) + 1); \
          key = umin32(key, (cl) == ci ? 0xFFFFFFFFu : klo); \
          key = umin32(key, (ch) == ci ? 0xFFFFFFFFu : khi); }
        ENT(ra.x, cj[0],  cj[1],  jb0 + 0) ENT(ra.y, cj[2],  cj[3],  jb0 + 2)
        ENT(ra.z, cj[4],  cj[5],  jb0 + 4) ENT(ra.w, cj[6],  cj[7],  jb0 + 6)
        ENT(rb.x, cj[8],  cj[9],  jb1 + 0) ENT(rb.y, cj[10], cj[11], jb1 + 2)
        ENT(rb.z, cj[12], cj[13], jb1 + 4) ENT(rb.w, cj[14], cj[15], jb1 + 6)
        #undef ENT

        #define DPPMIN(ctrl) { \
          unsigned tv = (unsigned)__builtin_amdgcn_update_dpp((int)key, (int)key, (ctrl), 0xF, 0xF, false); \
          key = umin32(key, tv); }
        DPPMIN(0x111) DPPMIN(0x112) DPPMIN(0x114) DPPMIN(0x118)
        DPPMIN(0x142) DPPMIN(0x143)
        #undef DPPMIN

        if (lane == 63 && key != 0xFFFFFFFFu) {
          unsigned wv = key >> 16, v = key & 0xFFFFu;
          unsigned cmin = umin32((unsigned)row, v);
          unsigned cmax = (unsigned)row + v - cmin;
          unsigned long long k64 =
              ((unsigned long long)wv << 20) | (unsigned long long)((cmin << 10) | cmax);
          atomicMin(&bestc[ci], k64);
        }
      }
    }

    // ---- per-cloud ticket barrier: last arriver merges ----
    __threadfence();
    __syncthreads();
    if (tid == 0) {
      unsigned my = atomicAdd(&bar[cloud], 1u);
      lastFlag = (my == 8u * (rnd + 1u) - 1u) ? 1u : 0u;
    }
    __syncthreads();

    if (lastFlag) {
      // ---- merge (256 thr x 4 nodes) ----
      unsigned long long bk[4];
      unsigned pa[4], wb[4];
      bool app[4];
      #pragma unroll
      for (int q = 0; q < 4; ++q) {
        int i = tid + q * 256;
        bk[q] = atomicMin(&bestc[i], BMAX);  // coherent read, value unchanged
        par[i] = (unsigned short)i;
      }
      __syncthreads();
      #pragma unroll
      for (int q = 0; q < 4; ++q) {
        int i = tid + q * 256;
        unsigned cold = comp16[i];
        pa[q] = (unsigned)i; wb[q] = 0;
        if (cold == (unsigned)i && bk[q] != BMAX) {
          wb[q] = (unsigned)(bk[q] >> 20) & 0xFFFFu;
          unsigned cmin = (unsigned)(bk[q] >> 10) & 1023u;
          unsigned cmax = (unsigned)bk[q] & 1023u;
          unsigned ca = comp16[cmin], cb = comp16[cmax];
          pa[q] = (ca == (unsigned)i) ? cb : ca;
          par[i] = (unsigned short)pa[q];
        }
      }
      __syncthreads();
      #pragma unroll
      for (int q = 0; q < 4; ++q) {
        int i = tid + q * 256;
        unsigned partner = pa[q];
        unsigned pp = par[partner];
        bool twoc = (partner != (unsigned)i) && (pp == (unsigned)i);
        bool winner = twoc && ((unsigned)i < partner);
        app[q] = (partner != (unsigned)i) && !winner;
        pa[q] = winner ? 1u : 0u;
      }
      __syncthreads();
      #pragma unroll
      for (int q = 0; q < 4; ++q) {
        int i = tid + q * 256;
        if (pa[q]) par[i] = (unsigned short)i;
        if (app[q]) {
          unsigned slot = atomicAdd(&dcnt[cloud], 1u);
          deaths[(size_t)cloud * NPTS + slot] =
              __half2float(__ushort_as_half((unsigned short)wb[q]));
        }
      }
      __syncthreads();
      for (int it = 0; it < 10; ++it) {
        unsigned np[4];
        #pragma unroll
        for (int q = 0; q < 4; ++q) { int i = tid + q * 256; np[q] = par[par[i]]; }
        __syncthreads();
        #pragma unroll
        for (int q = 0; q < 4; ++q) { int i = tid + q * 256; par[i] = (unsigned short)np[q]; }
        __syncthreads();
      }
      if (tid == 0) cnt_sh = 0;
      __syncthreads();
      #pragma unroll
      for (int q = 0; q < 4; ++q) {
        int i = tid + q * 256;
        unsigned newc = par[comp16[i]];
        atomicExch(&compc[i], newc);
        atomicExch(&bestc[i], BMAX);
        unsigned long long bl = __ballot(newc == (unsigned)i);
        if (lane == 0) atomicAdd(&cnt_sh, (unsigned)__popcll(bl));
      }
      __syncthreads();
      if (tid == 0) {
        atomicExch(&ncomp[cloud], cnt_sh);
        __threadfence();
        atomicExch(&gen[cloud], rnd + 1u);
      }
    } else {
      if (tid == 0) {
        while (atomicAdd(&gen[cloud], 0u) < rnd + 1u) __builtin_amdgcn_s_sleep(2);
      }
      __syncthreads();
    }

    if (tid == 0) exit_sh = atomicAdd(&ncomp[cloud], 0u);
    __syncthreads();
    if (exit_sh == 1u) return;
  }
}

// ---------------- bitonic sort kernel ----------------
__global__ __launch_bounds__(1024) void sort_kernel(float* __restrict__ buf) {
  __shared__ float s[NPTS];
  int tid = threadIdx.x;
  float* base = buf + (size_t)blockIdx.x * NPTS;
  s[tid] = base[tid];
  __syncthreads();
  for (int k = 2; k <= NPTS; k <<= 1) {
    for (int jj = k >> 1; jj > 0; jj >>= 1) {
      int i = tid;
      int l = i ^ jj;
      if (l > i) {
        float va = s[i], vb = s[l];
        bool up = ((i & k) == 0);
        if ((va > vb) == up) { s[i] = vb; s[l] = va; }
      }
      __syncthreads();
    }
  }
  base[tid] = s[tid];
}

// ---------------- fallback MSE kernel (small ws path) ----------------
__global__ __launch_bounds__(256) void mse_kernel(const float* __restrict__ a,
                                                  const float* __restrict__ b,
                                                  double* __restrict__ acc, int n4) {
  int i = blockIdx.x * blockDim.x + threadIdx.x;
  int stride = gridDim.x * blockDim.x;
  const float4* a4 = (const float4*)a;
  const float4* b4 = (const float4*)b;
  float s = 0.f;
  for (int k = i; k < n4; k += stride) {
    float4 va = a4[k], vb = b4[k];
    float dx = va.x - vb.x, dy = va.y - vb.y, dz = va.z - vb.z, dw = va.w - vb.w;
    s += dx * dx + dy * dy + dz * dz + dw * dw;
  }
  #pragma unroll
  for (int off = 32; off; off >>= 1) s += __shfl_xor(s, off);
  __shared__ float wsum[4];
  int lane = threadIdx.x & 63, wid = threadIdx.x >> 6;
  if (lane == 0) wsum[wid] = s;
  __syncthreads();
  if (threadIdx.x == 0)
    atomicAdd(acc, (double)(wsum[0] + wsum[1] + wsum[2] + wsum[3]));
}

// ---------------- fallback: fused Prim+sort from x (small ws) ----------------
__global__ __launch_bounds__(1024) void prim_kernel(const float* __restrict__ x1,
                                                    const float* __restrict__ x2,
                                                    float* __restrict__ sorted_out) {
  const int cloud = blockIdx.x;
  const int b = cloud & (BATCH - 1);
  const int src = cloud >> 4;
  const float* xbase = (src ? x2 : x1) + (size_t)b * NPTS * DIM;
  const int j = threadIdx.x;

  __shared__ float xi_sh[DIM];
  __shared__ float sq_sh[NPTS];
  __shared__ float redw[16];
  __shared__ int   redi[16];
  __shared__ float deaths[NPTS];

  const float4* xr = (const float4*)(xbase + (size_t)j * DIM);
  {
    float ax = 0.f, ay = 0.f, az = 0.f, aw = 0.f;
    #pragma unroll 8
    for (int m = 0; m < DIM / 4; ++m) {
      float4 v = xr[m];
      ax = fmaf(v.x, v.x, ax); ay = fmaf(v.y, v.y, ay);
      az = fmaf(v.z, v.z, az); aw = fmaf(v.w, v.w, aw);
    }
    sq_sh[j] = (ax + ay) + (az + aw);
  }
  const float sqj = sq_sh[j];

  float mind = BIGF;
  bool in_tree = (j == 0);
  int  cur = 0;

  for (int t = 0; t < NPTS - 1; ++t) {
    if (threadIdx.x < DIM / 4)
      ((float4*)xi_sh)[threadIdx.x] = ((const float4*)(xbase + (size_t)cur * DIM))[threadIdx.x];
    __syncthreads();

    const float4* xi4 = (const float4*)xi_sh;
    float ax = 0.f, ay = 0.f, az = 0.f, aw = 0.f;
    #pragma unroll 8
    for (int m = 0; m < DIM / 4; ++m) {
      float4 v = xr[m];
      float4 u = xi4[m];
      ax = fmaf(v.x, u.x, ax); ay = fmaf(v.y, u.y, ay);
      az = fmaf(v.z, u.z, az); aw = fmaf(v.w, u.w, aw);
    }
    float dot = (ax + ay) + (az + aw);
    float d2 = sq_sh[cur] + sqj - 2.f * dot;
    float d = sqrtf(fmaxf(d2, 0.f) + 1e-12f);
    mind = in_tree ? BIGF : fminf(mind, d);

    float w = mind;
    int idx = j;
    #pragma unroll
    for (int off = 32; off; off >>= 1) {
      float w2 = __shfl_xor(w, off);
      int i2 = __shfl_xor(idx, off);
      if (w2 < w || (w2 == w && i2 < idx)) { w = w2; idx = i2; }
    }
    int lane = j & 63, wid = j >> 6;
    if (lane == 0) { redw[wid] = w; redi[wid] = idx; }
    __syncthreads();

    float cw = redw[0];
    int ci = redi[0];
    #pragma unroll
    for (int q = 1; q < 16; ++q) {
      float w2 = redw[q]; int i2 = redi[q];
      if (w2 < cw || (w2 == cw && i2 < ci)) { cw = w2; ci = i2; }
    }
    if (j == ci) in_tree = true;
    if (j == 0)  deaths[t] = cw;
    cur = ci;
  }

  if (threadIdx.x == 0) deaths[NPTS - 1] = BIGF;
  __syncthreads();

  for (int k = 2; k <= NPTS; k <<= 1) {
    for (int jj = k >> 1; jj > 0; jj >>= 1) {
      int i = threadIdx.x;
      int l = i ^ jj;
      if (l > i) {
        float va = deaths[i], vb = deaths[l];
        bool up = ((i & k) == 0);
        if ((va > vb) == up) { deaths[i] = vb; deaths[l] = va; }
      }
      __syncthreads();
    }
  }
  sorted_out[(size_t)cloud * NPTS + threadIdx.x] = deaths[threadIdx.x];
}

// ---------------- final combine ----------------
__global__ __launch_bounds__(1024) void final_kernel(const double* __restrict__ mse_acc,
                                                     const float* __restrict__ sorted,
                                                     float* __restrict__ out) {
  int wid = threadIdx.x >> 6;
  int lane = threadIdx.x & 63;
  const float* s1 = sorted + (size_t)wid * NPTS;
  const float* s2 = sorted + (size_t)(BATCH + wid) * NPTS;
  float s = 0.f;
  for (int k = lane; k < NPTS; k += 64) {
    float dlt = s1[k] - s2[k];
    s += dlt * dlt;
  }
  #pragma unroll
  for (int off = 32; off; off >>= 1) s += __shfl_xor(s, off);
  __shared__ float part[16];
  if (lane == 0) part[wid] = sqrtf(s);
  __syncthreads();
  if (threadIdx.x == 0) {
    float topo = 0.f;
    #pragma unroll
    for (int q = 0; q < 16; ++q) topo += part[q];
    float mse = (float)(mse_acc[0] / (double)((size_t)BATCH * NPTS * DIM));
    out[0] = 1.0f * mse + 0.1f * topo;
  }
}

extern "C" void kernel_launch(void* const* d_in, const int* in_sizes, int n_in,
                              void* d_out, int out_size, void* d_ws, size_t ws_size,
                              hipStream_t stream) {
  const float* x1 = (const float*)d_in[0];
  const float* x2 = (const float*)d_in[1];
  double* mse_acc = (double*)d_ws;
  float* deaths   = (float*)((char*)d_ws + DEATHS_OFF);
  float* out      = (float*)d_out;

  hipMemsetAsync(d_ws, 0, 64, stream);

  if (ws_size >= WS_NEED) {
    unsigned short* Dmat = (unsigned short*)((char*)d_ws + D_OFF);
    unsigned short* xbf  = (unsigned short*)((char*)d_ws + XBF_OFF);
    float* sqg           = (float*)((char*)d_ws + SQ_OFF);
    unsigned* comp       = (unsigned*)((char*)d_ws + COMP_OFF);
    unsigned long long* best = (unsigned long long*)((char*)d_ws + BEST_OFF);
    unsigned* ncomp      = (unsigned*)((char*)d_ws + CNT_OFF);
    unsigned* dcnt       = ncomp + NCLOUD;
    unsigned* barg       = (unsigned*)((char*)d_ws + BAR_OFF);
    unsigned* bar        = barg;
    unsigned* gen        = barg + NCLOUD;

    prep_mse<<<dim3(BATCH, 8), 256, 0, stream>>>(x1, x2, xbf, sqg, comp, best,
                                                 ncomp, dcnt, deaths, barg, mse_acc);
    distmat_mfma<<<dim3(16, 16, NCLOUD), 256, 0, stream>>>(xbf, sqg, Dmat, best);
    boruvka_persist<<<dim3(8, NCLOUD), 256, 0, stream>>>(Dmat, comp, best, ncomp,
                                                         dcnt, deaths, bar, gen);
    sort_kernel<<<NCLOUD, 1024, 0, stream>>>(deaths);
  } else {
    int n4 = (BATCH * NPTS * DIM) / 4;
    mse_kernel<<<1024, 256, 0, stream>>>(x1, x2, mse_acc, n4);
    prim_kernel<<<NCLOUD, 1024, 0, stream>>>(x1, x2, deaths);
  }

  final_kernel<<<1, 1024, 0, stream>>>(mse_acc, deaths, out);
}

// Round 8
// 198.022 us; speedup vs baseline: 1.1963x; 1.1963x over previous
//
#include <hip/hip_runtime.h>
#include <hip/hip_fp16.h>
#include <math.h>

#define NPTS 1024
#define DIM  128
#define BATCH 16
#define NCLOUD 32
#define BIGF 3.0e38f
#define BMAX 0xFFFFFFFFFFFFFFFFull

// ws layout (fast path):
//   [0, 64)     : double mse_sum
//   DEATHS_OFF  : float deaths[32][1024]
//   D_OFF +64MB : fp16 D[32][1024][1024]
//   XBF_OFF+8MB : bf16 x[32][1024][128]
//   SQ_OFF      : f32 sq[32][1024]            (128 KB)
//   C4_OFF      : u64 comp4[32][256]          (64 KB, 4 comps/word)
//   BEST_OFF    : u64 best[32][1024]          (256 KB)
//   CAND_OFF    : uint2 cand[32][1024][16]    (4 MB, top-2 keys per stripe)
//   CNT_OFF     : u32 ncomp[32], u32 dcnt[32]
//   BAR_OFF     : u32 bar[32], u32 gen[32]
#define DEATHS_OFF 64
#define D_OFF 196608
#define XBF_OFF ((size_t)D_OFF + (size_t)NCLOUD * NPTS * NPTS * 2)
#define SQ_OFF   (XBF_OFF + (size_t)NCLOUD * NPTS * DIM * 2)
#define C4_OFF   (SQ_OFF + (size_t)NCLOUD * NPTS * 4)
#define BEST_OFF (C4_OFF + (size_t)NCLOUD * 256 * 8)
#define CAND_OFF (BEST_OFF + (size_t)NCLOUD * NPTS * 8)
#define CNT_OFF  (CAND_OFF + (size_t)NCLOUD * NPTS * 16 * 8)
#define BAR_OFF  (CNT_OFF + 256)
#define WS_NEED  (BAR_OFF + 256)

typedef __attribute__((ext_vector_type(8))) short short8;
typedef __attribute__((ext_vector_type(4))) float f32x4;

__device__ __forceinline__ unsigned umin32(unsigned a, unsigned b) { return a < b ? a : b; }
__device__ __forceinline__ unsigned umax32(unsigned a, unsigned b) { return a > b ? a : b; }

__device__ __forceinline__ unsigned bfbits(float f) {
  unsigned u = __float_as_uint(f);
  return (u + 0x7FFFu + ((u >> 16) & 1u)) >> 16;  // RNE, finite inputs
}

// ---------------- fused prep + MSE + state init ----------------
__global__ __launch_bounds__(256) void prep_mse(const float* __restrict__ x1,
                                                const float* __restrict__ x2,
                                                unsigned short* __restrict__ xbf,
                                                float* __restrict__ sqg,
                                                unsigned long long* __restrict__ comp4,
                                                unsigned long long* __restrict__ best,
                                                unsigned* __restrict__ ncomp,
                                                unsigned* __restrict__ dcnt,
                                                float* __restrict__ deaths,
                                                unsigned* __restrict__ barg,
                                                double* __restrict__ acc) {
  const int b = blockIdx.x;
  const int s = blockIdx.y;
  const int tid = threadIdx.x;

  if (s == 0 && tid == 0) {
    ncomp[b] = NPTS; ncomp[16 + b] = NPTS;
    dcnt[b] = 0; dcnt[16 + b] = 0;
    deaths[(size_t)b * NPTS + NPTS - 1] = BIGF;
    deaths[(size_t)(16 + b) * NPTS + NPTS - 1] = BIGF;
  }
  if (b == 0 && s == 0 && tid < 64) barg[tid] = 0;  // bar[32] + gen[32]

  const int half = tid >> 7;
  const int r = s * 128 + (tid & 127);
  const int cloud = half * 16 + b;
  const float* xc = (half ? x2 : x1) + (size_t)b * NPTS * DIM;
  const float4* xr = (const float4*)(xc + (size_t)r * DIM);
  const float4* yr = (const float4*)(x2 + (size_t)b * NPTS * DIM + (size_t)r * DIM);
  uint4* orow = (uint4*)xbf + (size_t)cloud * NPTS * (DIM / 8) + (size_t)r * (DIM / 8);

  float mse_s = 0.f;
  float ax = 0.f, ay = 0.f, az = 0.f, aw = 0.f;
  #pragma unroll 4
  for (int m = 0; m < 32; m += 2) {
    float4 v0 = xr[m], v1 = xr[m + 1];
    ax = fmaf(v0.x, v0.x, ax); ay = fmaf(v0.y, v0.y, ay);
    az = fmaf(v0.z, v0.z, az); aw = fmaf(v0.w, v0.w, aw);
    ax = fmaf(v1.x, v1.x, ax); ay = fmaf(v1.y, v1.y, ay);
    az = fmaf(v1.z, v1.z, az); aw = fmaf(v1.w, v1.w, aw);
    uint4 o;
    o.x = bfbits(v0.x) | (bfbits(v0.y) << 16);
    o.y = bfbits(v0.z) | (bfbits(v0.w) << 16);
    o.z = bfbits(v1.x) | (bfbits(v1.y) << 16);
    o.w = bfbits(v1.z) | (bfbits(v1.w) << 16);
    orow[m >> 1] = o;
    if (half == 0) {
      float4 u0 = yr[m], u1 = yr[m + 1];
      float d0 = v0.x - u0.x, d1 = v0.y - u0.y, d2 = v0.z - u0.z, d3 = v0.w - u0.w;
      float e0 = v1.x - u1.x, e1 = v1.y - u1.y, e2 = v1.z - u1.z, e3 = v1.w - u1.w;
      mse_s += d0 * d0 + d1 * d1 + d2 * d2 + d3 * d3;
      mse_s += e0 * e0 + e1 * e1 + e2 * e2 + e3 * e3;
    }
  }
  sqg[cloud * NPTS + r] = (ax + ay) + (az + aw);
  best[cloud * NPTS + r] = BMAX;
  if ((r & 3) == 0) {
    unsigned long long pk = (unsigned long long)r |
                            ((unsigned long long)(r + 1) << 16) |
                            ((unsigned long long)(r + 2) << 32) |
                            ((unsigned long long)(r + 3) << 48);
    comp4[cloud * 256 + (r >> 2)] = pk;
  }

  #pragma unroll
  for (int off = 32; off; off >>= 1) mse_s += __shfl_xor(mse_s, off);
  __shared__ float wsum[4];
  int lane = tid & 63, wid = tid >> 6;
  if (lane == 0) wsum[wid] = mse_s;
  __syncthreads();
  if (tid == 0)
    atomicAdd(acc, (double)(wsum[0] + wsum[1] + wsum[2] + wsum[3]));
}

// ---------------- MFMA distance matrix + top-2-per-stripe candidates + fused r1 ----
__global__ __launch_bounds__(256) void distmat_mfma(const unsigned short* __restrict__ xbf,
                                                    const float* __restrict__ sqg,
                                                    unsigned short* __restrict__ Dmat,
                                                    unsigned long long* __restrict__ best,
                                                    uint2* __restrict__ cand) {
  const int cloud = blockIdx.z;
  const int i0 = blockIdx.y * 64;
  const int j0 = blockIdx.x * 64;
  const int tid = threadIdx.x;
  const int lane = tid & 63, w = tid >> 6;
  const int l15 = lane & 15, kq = lane >> 4;

  __shared__ unsigned short Ash[64 * 128];
  __shared__ unsigned short Bsh[64 * 128];
  __shared__ float sqi_sh[64], sqj_sh[64];

  const uint4* xg = (const uint4*)xbf + (size_t)cloud * NPTS * (DIM / 8);
  uint4* A4 = (uint4*)Ash;
  uint4* B4 = (uint4*)Bsh;

  #pragma unroll
  for (int c = tid; c < 1024; c += 256) {
    int row = c >> 4, c16 = c & 15;
    int sidx = (row << 4) | (c16 ^ (row & 7));
    A4[sidx] = xg[((size_t)(i0 + row) << 4) | c16];
    B4[sidx] = xg[((size_t)(j0 + row) << 4) | c16];
  }
  if (tid < 64) sqi_sh[tid] = sqg[(size_t)cloud * NPTS + i0 + tid];
  else if (tid < 128) sqj_sh[tid - 64] = sqg[(size_t)cloud * NPTS + j0 + tid - 64];
  __syncthreads();

  const int ar = w * 16 + l15;
  f32x4 acc[4];
  #pragma unroll
  for (int jt = 0; jt < 4; ++jt) acc[jt] = (f32x4){0.f, 0.f, 0.f, 0.f};

  #pragma unroll
  for (int kk = 0; kk < 4; ++kk) {
    int acol = (kk * 4 + kq) ^ (ar & 7);
    short8 a = *(const short8*)&A4[(ar << 4) | acol];
    #pragma unroll
    for (int jt = 0; jt < 4; ++jt) {
      int br = jt * 16 + l15;
      int bcol = (kk * 4 + kq) ^ (br & 7);
      short8 bf = *(const short8*)&B4[(br << 4) | bcol];
      acc[jt] = __builtin_amdgcn_mfma_f32_16x16x32_bf16(a, bf, acc[jt], 0, 0, 0);
    }
  }

  unsigned short* Dc = Dmat + ((size_t)cloud << 20);
  unsigned long long* bestc = best + cloud * NPTS;

  unsigned k1[4] = {0xFFFFFFFFu, 0xFFFFFFFFu, 0xFFFFFFFFu, 0xFFFFFFFFu};
  unsigned k2[4] = {0xFFFFFFFFu, 0xFFFFFFFFu, 0xFFFFFFFFu, 0xFFFFFFFFu};

  #pragma unroll
  for (int jt = 0; jt < 4; ++jt) {
    int jl = jt * 16 + l15;
    int gj = j0 + jl;
    float sqj = sqj_sh[jl];
    #pragma unroll
    for (int r = 0; r < 4; ++r) {
      int il = w * 16 + kq * 4 + r;
      int gi = i0 + il;
      float d2 = sqi_sh[il] + sqj - 2.f * acc[jt][r];
      float d = sqrtf(fmaxf(d2, 0.f) + 1e-12f);
      unsigned h = (gi == gj) ? 0x7C00u : (unsigned)__half_as_ushort(__float2half(d));
      Dc[(size_t)gi * NPTS + gj] = (unsigned short)h;
      unsigned key = (h << 16) | (unsigned)gj;
      if (key < k1[r]) { k2[r] = k1[r]; k1[r] = key; }
      else if (key < k2[r]) k2[r] = key;
    }
  }

  // merge top-2 pairs across the 16-lane col group
  #pragma unroll
  for (int mask = 1; mask < 16; mask <<= 1) {
    #pragma unroll
    for (int r = 0; r < 4; ++r) {
      unsigned o1 = __shfl_xor(k1[r], mask);
      unsigned o2 = __shfl_xor(k2[r], mask);
      unsigned n1 = umin32(k1[r], o1);
      unsigned n2 = umin32(umax32(k1[r], o1), umin32(k2[r], o2));
      k1[r] = n1; k2[r] = n2;
    }
  }

  if (l15 == 0) {
    #pragma unroll
    for (int r = 0; r < 4; ++r) {
      unsigned gi = (unsigned)(i0 + w * 16 + kq * 4 + r);
      cand[(((size_t)cloud << 10) + gi) * 16 + blockIdx.x] = make_uint2(k1[r], k2[r]);
      // fused Boruvka round-1 (k1 == stripe min)
      unsigned j = k1[r] & 0xFFFFu, hv = k1[r] >> 16;
      unsigned cmn = umin32(gi, j);
      unsigned cmx = gi + j - cmn;
      unsigned long long k64 =
          ((unsigned long long)hv << 20) | (unsigned long long)((cmn << 10) | cmx);
      atomicMin(&bestc[gi], k64);
    }
  }
}

// ---------------- persistent Boruvka: candidate rounds + certified fallback ----------------
__global__ __launch_bounds__(256) void boruvka_persist(const unsigned short* __restrict__ Dmat,
                                                       const uint2* __restrict__ cand,
                                                       unsigned long long* __restrict__ comp4,
                                                       unsigned long long* __restrict__ best,
                                                       unsigned* __restrict__ ncomp,
                                                       unsigned* __restrict__ dcnt,
                                                       float* __restrict__ deaths,
                                                       unsigned* __restrict__ bar,
                                                       unsigned* __restrict__ gen) {
  const int cloud = blockIdx.y;
  const int bx = blockIdx.x;
  const int tid = threadIdx.x;
  const int lane = tid & 63, wid = tid >> 6;
  unsigned long long* comp4c = comp4 + cloud * 256;
  unsigned long long* bestc = best + cloud * NPTS;
  const uint4* p = (const uint4*)(Dmat + ((size_t)cloud << 20));
  const uint2* candc = cand + ((size_t)cloud << 10) * 16;
  const unsigned jb0 = (unsigned)(lane << 3), jb1 = 512u + jb0;

  __shared__ unsigned short comp16[NPTS];
  __shared__ unsigned short par[NPTS];
  __shared__ unsigned lastFlag, cnt_sh, exit_sh;

  for (unsigned rnd = 0; rnd < 11; ++rnd) {
    // coherent reload of comp (packed u64, 4 comps/word)
    if (tid < 256) {
      unsigned long long wv = atomicAdd(&comp4c[tid], 0ull);
      comp16[4 * tid + 0] = (unsigned short)(wv & 0xFFFFu);
      comp16[4 * tid + 1] = (unsigned short)((wv >> 16) & 0xFFFFu);
      comp16[4 * tid + 2] = (unsigned short)((wv >> 32) & 0xFFFFu);
      comp16[4 * tid + 3] = (unsigned short)((wv >> 48) & 0xFFFFu);
    }
    __syncthreads();

    if (rnd > 0) {
      // ---- candidate phase: 4 rows per wave-iter, 16 lanes (stripes) per row ----
      const int sub = lane >> 4, stripe = lane & 15;
      const int rowbase = bx * 128 + wid * 32;
      for (int it = 0; it < 8; ++it) {
        int row = rowbase + it * 4 + sub;
        unsigned ci = (unsigned)comp16[row];
        uint2 c = candc[(size_t)row * 16 + stripe];
        unsigned j1 = c.x & 0xFFFFu, j2 = c.y & 0xFFFFu;
        bool o1 = ((unsigned)comp16[j1] != ci);
        bool o2 = ((unsigned)comp16[j2] != ci);
        unsigned e = o1 ? c.x : (o2 ? c.y : 0xFFFFFFFFu);
        unsigned bw = (!o1 && !o2) ? (c.y >> 16) : 0xFFFFu;
        #pragma unroll
        for (int mask = 1; mask < 16; mask <<= 1) {
          e = umin32(e, __shfl_xor(e, mask));
          bw = umin32(bw, __shfl_xor(bw, mask));
        }
        bool resolved = (e >> 16) < bw;  // strict: hidden edges provably heavier
        unsigned long long unres = __ballot(!resolved);
        if (resolved && stripe == 0 && e != 0xFFFFFFFFu) {
          unsigned j = e & 0xFFFFu, hv = e >> 16;
          unsigned cmn = umin32((unsigned)row, j);
          unsigned cmx = (unsigned)row + j - cmn;
          unsigned long long k64 =
              ((unsigned long long)hv << 20) | (unsigned long long)((cmn << 10) | cmx);
          atomicMin(&bestc[ci], k64);
        }
        if (unres) {
          // full-row rescan (exact) for unresolved rows of this group
          unsigned cj[16];
          #pragma unroll
          for (int q = 0; q < 8; ++q) cj[q] = comp16[(lane << 3) + q];
          #pragma unroll
          for (int q = 0; q < 8; ++q) cj[8 + q] = comp16[512 + (lane << 3) + q];
          #pragma unroll
          for (int s = 0; s < 4; ++s) {
            if (!((unres >> (s * 16)) & 1ull)) continue;
            int frow = rowbase + it * 4 + s;
            unsigned fci = (unsigned)comp16[frow];
            uint4 ra = p[frow * 128 + lane];
            uint4 rb = p[frow * 128 + 64 + lane];
            unsigned key = 0xFFFFFFFFu;
            #define ENT(word, cl, ch, jb) { \
              unsigned klo = ((word) << 16) | (jb); \
              unsigned khi = ((word) & 0xFFFF0000u) | ((jb) + 1); \
              key = umin32(key, (cl) == fci ? 0xFFFFFFFFu : klo); \
              key = umin32(key, (ch) == fci ? 0xFFFFFFFFu : khi); }
            ENT(ra.x, cj[0],  cj[1],  jb0 + 0) ENT(ra.y, cj[2],  cj[3],  jb0 + 2)
            ENT(ra.z, cj[4],  cj[5],  jb0 + 4) ENT(ra.w, cj[6],  cj[7],  jb0 + 6)
            ENT(rb.x, cj[8],  cj[9],  jb1 + 0) ENT(rb.y, cj[10], cj[11], jb1 + 2)
            ENT(rb.z, cj[12], cj[13], jb1 + 4) ENT(rb.w, cj[14], cj[15], jb1 + 6)
            #undef ENT
            #define DPPMIN(ctrl) { \
              unsigned tv = (unsigned)__builtin_amdgcn_update_dpp((int)key, (int)key, (ctrl), 0xF, 0xF, false); \
              key = umin32(key, tv); }
            DPPMIN(0x111) DPPMIN(0x112) DPPMIN(0x114) DPPMIN(0x118)
            DPPMIN(0x142) DPPMIN(0x143)
            #undef DPPMIN
            if (lane == 63 && key != 0xFFFFFFFFu) {
              unsigned wv = key >> 16, v = key & 0xFFFFu;
              unsigned cmn = umin32((unsigned)frow, v);
              unsigned cmx = (unsigned)frow + v - cmn;
              unsigned long long k64 =
                  ((unsigned long long)wv << 20) | (unsigned long long)((cmn << 10) | cmx);
              atomicMin(&bestc[fci], k64);
            }
          }
        }
      }
    }

    // ---- per-cloud ticket barrier: last arriver merges ----
    __threadfence();
    __syncthreads();
    if (tid == 0) {
      unsigned my = atomicAdd(&bar[cloud], 1u);
      lastFlag = (my == 8u * (rnd + 1u) - 1u) ? 1u : 0u;
    }
    __syncthreads();

    if (lastFlag) {
      // ---- merge (256 thr x 4 nodes) ----
      unsigned long long bk[4];
      unsigned pa[4], wb[4];
      bool app[4];
      #pragma unroll
      for (int q = 0; q < 4; ++q) {
        int i = tid + q * 256;
        bk[q] = atomicMin(&bestc[i], BMAX);  // coherent read, value unchanged
        par[i] = (unsigned short)i;
      }
      __syncthreads();
      #pragma unroll
      for (int q = 0; q < 4; ++q) {
        int i = tid + q * 256;
        unsigned cold = comp16[i];
        pa[q] = (unsigned)i; wb[q] = 0;
        if (cold == (unsigned)i && bk[q] != BMAX) {
          wb[q] = (unsigned)(bk[q] >> 20) & 0xFFFFu;
          unsigned cmin = (unsigned)(bk[q] >> 10) & 1023u;
          unsigned cmax = (unsigned)bk[q] & 1023u;
          unsigned ca = comp16[cmin], cb = comp16[cmax];
          pa[q] = (ca == (unsigned)i) ? cb : ca;
          par[i] = (unsigned short)pa[q];
        }
      }
      __syncthreads();
      #pragma unroll
      for (int q = 0; q < 4; ++q) {
        int i = tid + q * 256;
        unsigned partner = pa[q];
        unsigned pp = par[partner];
        bool twoc = (partner != (unsigned)i) && (pp == (unsigned)i);
        bool winner = twoc && ((unsigned)i < partner);
        app[q] = (partner != (unsigned)i) && !winner;
        pa[q] = winner ? 1u : 0u;
      }
      __syncthreads();
      #pragma unroll
      for (int q = 0; q < 4; ++q) {
        int i = tid + q * 256;
        if (pa[q]) par[i] = (unsigned short)i;
        if (app[q]) {
          unsigned slot = atomicAdd(&dcnt[cloud], 1u);
          deaths[(size_t)cloud * NPTS + slot] =
              __half2float(__ushort_as_half((unsigned short)wb[q]));
        }
      }
      __syncthreads();
      for (int it = 0; it < 10; ++it) {
        unsigned np[4];
        #pragma unroll
        for (int q = 0; q < 4; ++q) { int i = tid + q * 256; np[q] = par[par[i]]; }
        __syncthreads();
        #pragma unroll
        for (int q = 0; q < 4; ++q) { int i = tid + q * 256; par[i] = (unsigned short)np[q]; }
        __syncthreads();
      }
      if (tid == 0) cnt_sh = 0;
      __syncthreads();
      {
        unsigned rootcnt = 0;
        unsigned long long packed = 0;
        #pragma unroll
        for (int q = 0; q < 4; ++q) {
          int i = 4 * tid + q;
          unsigned newc = par[comp16[i]];
          packed |= (unsigned long long)newc << (16 * q);
          rootcnt += (newc == (unsigned)i) ? 1u : 0u;
          atomicExch(&bestc[i], BMAX);
        }
        atomicExch(&comp4c[tid], packed);
        #pragma unroll
        for (int off = 32; off; off >>= 1) rootcnt += __shfl_xor(rootcnt, off);
        if (lane == 0) atomicAdd(&cnt_sh, rootcnt);
      }
      __syncthreads();
      if (tid == 0) {
        atomicExch(&ncomp[cloud], cnt_sh);
        __threadfence();
        atomicExch(&gen[cloud], rnd + 1u);
      }
    } else {
      if (tid == 0) {
        while (atomicAdd(&gen[cloud], 0u) < rnd + 1u) __builtin_amdgcn_s_sleep(8);
      }
      __syncthreads();
    }

    if (tid == 0) exit_sh = atomicAdd(&ncomp[cloud], 0u);
    __syncthreads();
    if (exit_sh == 1u) return;
  }
}

// ---------------- bitonic sort kernel ----------------
__global__ __launch_bounds__(1024) void sort_kernel(float* __restrict__ buf) {
  __shared__ float s[NPTS];
  int tid = threadIdx.x;
  float* base = buf + (size_t)blockIdx.x * NPTS;
  s[tid] = base[tid];
  __syncthreads();
  for (int k = 2; k <= NPTS; k <<= 1) {
    for (int jj = k >> 1; jj > 0; jj >>= 1) {
      int i = tid;
      int l = i ^ jj;
      if (l > i) {
        float va = s[i], vb = s[l];
        bool up = ((i & k) == 0);
        if ((va > vb) == up) { s[i] = vb; s[l] = va; }
      }
      __syncthreads();
    }
  }
  base[tid] = s[tid];
}

// ---------------- fallback MSE kernel (small ws path) ----------------
__global__ __launch_bounds__(256) void mse_kernel(const float* __restrict__ a,
                                                  const float* __restrict__ b,
                                                  double* __restrict__ acc, int n4) {
  int i = blockIdx.x * blockDim.x + threadIdx.x;
  int stride = gridDim.x * blockDim.x;
  const float4* a4 = (const float4*)a;
  const float4* b4 = (const float4*)b;
  float s = 0.f;
  for (int k = i; k < n4; k += stride) {
    float4 va = a4[k], vb = b4[k];
    float dx = va.x - vb.x, dy = va.y - vb.y, dz = va.z - vb.z, dw = va.w - vb.w;
    s += dx * dx + dy * dy + dz * dz + dw * dw;
  }
  #pragma unroll
  for (int off = 32; off; off >>= 1) s += __shfl_xor(s, off);
  __shared__ float wsum[4];
  int lane = threadIdx.x & 63, wid = threadIdx.x >> 6;
  if (lane == 0) wsum[wid] = s;
  __syncthreads();
  if (threadIdx.x == 0)
    atomicAdd(acc, (double)(wsum[0] + wsum[1] + wsum[2] + wsum[3]));
}

// ---------------- fallback: fused Prim+sort from x (small ws) ----------------
__global__ __launch_bounds__(1024) void prim_kernel(const float* __restrict__ x1,
                                                    const float* __restrict__ x2,
                                                    float* __restrict__ sorted_out) {
  const int cloud = blockIdx.x;
  const int b = cloud & (BATCH - 1);
  const int src = cloud >> 4;
  const float* xbase = (src ? x2 : x1) + (size_t)b * NPTS * DIM;
  const int j = threadIdx.x;

  __shared__ float xi_sh[DIM];
  __shared__ float sq_sh[NPTS];
  __shared__ float redw[16];
  __shared__ int   redi[16];
  __shared__ float deaths[NPTS];

  const float4* xr = (const float4*)(xbase + (size_t)j * DIM);
  {
    float ax = 0.f, ay = 0.f, az = 0.f, aw = 0.f;
    #pragma unroll 8
    for (int m = 0; m < DIM / 4; ++m) {
      float4 v = xr[m];
      ax = fmaf(v.x, v.x, ax); ay = fmaf(v.y, v.y, ay);
      az = fmaf(v.z, v.z, az); aw = fmaf(v.w, v.w, aw);
    }
    sq_sh[j] = (ax + ay) + (az + aw);
  }
  const float sqj = sq_sh[j];

  float mind = BIGF;
  bool in_tree = (j == 0);
  int  cur = 0;

  for (int t = 0; t < NPTS - 1; ++t) {
    if (threadIdx.x < DIM / 4)
      ((float4*)xi_sh)[threadIdx.x] = ((const float4*)(xbase + (size_t)cur * DIM))[threadIdx.x];
    __syncthreads();

    const float4* xi4 = (const float4*)xi_sh;
    float ax = 0.f, ay = 0.f, az = 0.f, aw = 0.f;
    #pragma unroll 8
    for (int m = 0; m < DIM / 4; ++m) {
      float4 v = xr[m];
      float4 u = xi4[m];
      ax = fmaf(v.x, u.x, ax); ay = fmaf(v.y, u.y, ay);
      az = fmaf(v.z, u.z, az); aw = fmaf(v.w, u.w, aw);
    }
    float dot = (ax + ay) + (az + aw);
    float d2 = sq_sh[cur] + sqj - 2.f * dot;
    float d = sqrtf(fmaxf(d2, 0.f) + 1e-12f);
    mind = in_tree ? BIGF : fminf(mind, d);

    float w = mind;
    int idx = j;
    #pragma unroll
    for (int off = 32; off; off >>= 1) {
      float w2 = __shfl_xor(w, off);
      int i2 = __shfl_xor(idx, off);
      if (w2 < w || (w2 == w && i2 < idx)) { w = w2; idx = i2; }
    }
    int lane = j & 63, wid = j >> 6;
    if (lane == 0) { redw[wid] = w; redi[wid] = idx; }
    __syncthreads();

    float cw = redw[0];
    int ci = redi[0];
    #pragma unroll
    for (int q = 1; q < 16; ++q) {
      float w2 = redw[q]; int i2 = redi[q];
      if (w2 < cw || (w2 == cw && i2 < ci)) { cw = w2; ci = i2; }
    }
    if (j == ci) in_tree = true;
    if (j == 0)  deaths[t] = cw;
    cur = ci;
  }

  if (threadIdx.x == 0) deaths[NPTS - 1] = BIGF;
  __syncthreads();

  for (int k = 2; k <= NPTS; k <<= 1) {
    for (int jj = k >> 1; jj > 0; jj >>= 1) {
      int i = threadIdx.x;
      int l = i ^ jj;
      if (l > i) {
        float va = deaths[i], vb = deaths[l];
        bool up = ((i & k) == 0);
        if ((va > vb) == up) { deaths[i] = vb; deaths[l] = va; }
      }
      __syncthreads();
    }
  }
  sorted_out[(size_t)cloud * NPTS + threadIdx.x] = deaths[threadIdx.x];
}

// ---------------- final combine ----------------
__global__ __launch_bounds__(1024) void final_kernel(const double* __restrict__ mse_acc,
                                                     const float* __restrict__ sorted,
                                                     float* __restrict__ out) {
  int wid = threadIdx.x >> 6;
  int lane = threadIdx.x & 63;
  const float* s1 = sorted + (size_t)wid * NPTS;
  const float* s2 = sorted + (size_t)(BATCH + wid) * NPTS;
  float s = 0.f;
  for (int k = lane; k < NPTS; k += 64) {
    float dlt = s1[k] - s2[k];
    s += dlt * dlt;
  }
  #pragma unroll
  for (int off = 32; off; off >>= 1) s += __shfl_xor(s, off);
  __shared__ float part[16];
  if (lane == 0) part[wid] = sqrtf(s);
  __syncthreads();
  if (threadIdx.x == 0) {
    float topo = 0.f;
    #pragma unroll
    for (int q = 0; q < 16; ++q) topo += part[q];
    float mse = (float)(mse_acc[0] / (double)((size_t)BATCH * NPTS * DIM));
    out[0] = 1.0f * mse + 0.1f * topo;
  }
}

extern "C" void kernel_launch(void* const* d_in, const int* in_sizes, int n_in,
                              void* d_out, int out_size, void* d_ws, size_t ws_size,
                              hipStream_t stream) {
  const float* x1 = (const float*)d_in[0];
  const float* x2 = (const float*)d_in[1];
  double* mse_acc = (double*)d_ws;
  float* deaths   = (float*)((char*)d_ws + DEATHS_OFF);
  float* out      = (float*)d_out;

  hipMemsetAsync(d_ws, 0, 64, stream);

  if (ws_size >= WS_NEED) {
    unsigned short* Dmat = (unsigned short*)((char*)d_ws + D_OFF);
    unsigned short* xbf  = (unsigned short*)((char*)d_ws + XBF_OFF);
    float* sqg           = (float*)((char*)d_ws + SQ_OFF);
    unsigned long long* comp4 = (unsigned long long*)((char*)d_ws + C4_OFF);
    unsigned long long* best  = (unsigned long long*)((char*)d_ws + BEST_OFF);
    uint2* cand          = (uint2*)((char*)d_ws + CAND_OFF);
    unsigned* ncomp      = (unsigned*)((char*)d_ws + CNT_OFF);
    unsigned* dcnt       = ncomp + NCLOUD;
    unsigned* barg       = (unsigned*)((char*)d_ws + BAR_OFF);
    unsigned* bar        = barg;
    unsigned* gen        = barg + NCLOUD;

    prep_mse<<<dim3(BATCH, 8), 256, 0, stream>>>(x1, x2, xbf, sqg, comp4, best,
                                                 ncomp, dcnt, deaths, barg, mse_acc);
    distmat_mfma<<<dim3(16, 16, NCLOUD), 256, 0, stream>>>(xbf, sqg, Dmat, best, cand);
    boruvka_persist<<<dim3(8, NCLOUD), 256, 0, stream>>>(Dmat, cand, comp4, best, ncomp,
                                                         dcnt, deaths, bar, gen);
    sort_kernel<<<NCLOUD, 1024, 0, stream>>>(deaths);
  } else {
    int n4 = (BATCH * NPTS * DIM) / 4;
    mse_kernel<<<1024, 256, 0, stream>>>(x1, x2, mse_acc, n4);
    prim_kernel<<<NCLOUD, 1024, 0, stream>>>(x1, x2, deaths);
  }

  final_kernel<<<1, 1024, 0, stream>>>(mse_acc, deaths, out);
}

// Round 9
// 140.351 us; speedup vs baseline: 1.6879x; 1.4109x over previous
//
#include <hip/hip_runtime.h>
#include <hip/hip_fp16.h>
#include <math.h>

#define NPTS 1024
#define DIM  128
#define BATCH 16
#define NCLOUD 32
#define BIGF 3.0e38f
#define BMAX 0xFFFFFFFFFFFFFFFFull

// ws layout (fast path):
//   [0, 64)     : double mse_sum
//   DEATHS_OFF  : float deaths[32][1024] (sorted)
//   D_OFF +64MB : fp16 D[32][1024][1024]
//   XBF_OFF+8MB : bf16 x[32][1024][128]
//   SQ_OFF      : f32 sq[32][1024]
//   BEST_OFF    : u64 best[32][1024]        (round-1 best from distmat)
//   CAND_OFF    : uint2 cand[32][16][1024]  (4 MB, stripe-major top-2 keys)
#define DEATHS_OFF 64
#define D_OFF 196608
#define XBF_OFF ((size_t)D_OFF + (size_t)NCLOUD * NPTS * NPTS * 2)
#define SQ_OFF   (XBF_OFF + (size_t)NCLOUD * NPTS * DIM * 2)
#define BEST_OFF (SQ_OFF + (size_t)NCLOUD * NPTS * 4)
#define CAND_OFF (BEST_OFF + (size_t)NCLOUD * NPTS * 8)
#define WS_NEED  (CAND_OFF + (size_t)NCLOUD * NPTS * 16 * 8)

typedef __attribute__((ext_vector_type(8))) short short8;
typedef __attribute__((ext_vector_type(4))) float f32x4;

__device__ __forceinline__ unsigned umin32(unsigned a, unsigned b) { return a < b ? a : b; }
__device__ __forceinline__ unsigned umax32(unsigned a, unsigned b) { return a > b ? a : b; }

__device__ __forceinline__ unsigned bfbits(float f) {
  unsigned u = __float_as_uint(f);
  return (u + 0x7FFFu + ((u >> 16) & 1u)) >> 16;  // RNE, finite inputs
}

// ---------------- fused prep + MSE + state init ----------------
__global__ __launch_bounds__(256) void prep_mse(const float* __restrict__ x1,
                                                const float* __restrict__ x2,
                                                unsigned short* __restrict__ xbf,
                                                float* __restrict__ sqg,
                                                unsigned long long* __restrict__ best,
                                                double* __restrict__ acc) {
  const int b = blockIdx.x;
  const int s = blockIdx.y;
  const int tid = threadIdx.x;

  const int half = tid >> 7;
  const int r = s * 128 + (tid & 127);
  const int cloud = half * 16 + b;
  const float* xc = (half ? x2 : x1) + (size_t)b * NPTS * DIM;
  const float4* xr = (const float4*)(xc + (size_t)r * DIM);
  const float4* yr = (const float4*)(x2 + (size_t)b * NPTS * DIM + (size_t)r * DIM);
  uint4* orow = (uint4*)xbf + (size_t)cloud * NPTS * (DIM / 8) + (size_t)r * (DIM / 8);

  float mse_s = 0.f;
  float ax = 0.f, ay = 0.f, az = 0.f, aw = 0.f;
  #pragma unroll 4
  for (int m = 0; m < 32; m += 2) {
    float4 v0 = xr[m], v1 = xr[m + 1];
    ax = fmaf(v0.x, v0.x, ax); ay = fmaf(v0.y, v0.y, ay);
    az = fmaf(v0.z, v0.z, az); aw = fmaf(v0.w, v0.w, aw);
    ax = fmaf(v1.x, v1.x, ax); ay = fmaf(v1.y, v1.y, ay);
    az = fmaf(v1.z, v1.z, az); aw = fmaf(v1.w, v1.w, aw);
    uint4 o;
    o.x = bfbits(v0.x) | (bfbits(v0.y) << 16);
    o.y = bfbits(v0.z) | (bfbits(v0.w) << 16);
    o.z = bfbits(v1.x) | (bfbits(v1.y) << 16);
    o.w = bfbits(v1.z) | (bfbits(v1.w) << 16);
    orow[m >> 1] = o;
    if (half == 0) {
      float4 u0 = yr[m], u1 = yr[m + 1];
      float d0 = v0.x - u0.x, d1 = v0.y - u0.y, d2 = v0.z - u0.z, d3 = v0.w - u0.w;
      float e0 = v1.x - u1.x, e1 = v1.y - u1.y, e2 = v1.z - u1.z, e3 = v1.w - u1.w;
      mse_s += d0 * d0 + d1 * d1 + d2 * d2 + d3 * d3;
      mse_s += e0 * e0 + e1 * e1 + e2 * e2 + e3 * e3;
    }
  }
  sqg[cloud * NPTS + r] = (ax + ay) + (az + aw);
  best[cloud * NPTS + r] = BMAX;

  #pragma unroll
  for (int off = 32; off; off >>= 1) mse_s += __shfl_xor(mse_s, off);
  __shared__ float wsum[4];
  int lane = tid & 63, wid = tid >> 6;
  if (lane == 0) wsum[wid] = mse_s;
  __syncthreads();
  if (tid == 0)
    atomicAdd(acc, (double)(wsum[0] + wsum[1] + wsum[2] + wsum[3]));
}

// ---------------- MFMA distance matrix + top-2-per-stripe candidates + fused r1 ----
__global__ __launch_bounds__(256) void distmat_mfma(const unsigned short* __restrict__ xbf,
                                                    const float* __restrict__ sqg,
                                                    unsigned short* __restrict__ Dmat,
                                                    unsigned long long* __restrict__ best,
                                                    uint2* __restrict__ cand) {
  const int cloud = blockIdx.z;
  const int i0 = blockIdx.y * 64;
  const int j0 = blockIdx.x * 64;
  const int tid = threadIdx.x;
  const int lane = tid & 63, w = tid >> 6;
  const int l15 = lane & 15, kq = lane >> 4;

  __shared__ unsigned short Ash[64 * 128];
  __shared__ unsigned short Bsh[64 * 128];
  __shared__ float sqi_sh[64], sqj_sh[64];

  const uint4* xg = (const uint4*)xbf + (size_t)cloud * NPTS * (DIM / 8);
  uint4* A4 = (uint4*)Ash;
  uint4* B4 = (uint4*)Bsh;

  #pragma unroll
  for (int c = tid; c < 1024; c += 256) {
    int row = c >> 4, c16 = c & 15;
    int sidx = (row << 4) | (c16 ^ (row & 7));
    A4[sidx] = xg[((size_t)(i0 + row) << 4) | c16];
    B4[sidx] = xg[((size_t)(j0 + row) << 4) | c16];
  }
  if (tid < 64) sqi_sh[tid] = sqg[(size_t)cloud * NPTS + i0 + tid];
  else if (tid < 128) sqj_sh[tid - 64] = sqg[(size_t)cloud * NPTS + j0 + tid - 64];
  __syncthreads();

  const int ar = w * 16 + l15;
  f32x4 acc[4];
  #pragma unroll
  for (int jt = 0; jt < 4; ++jt) acc[jt] = (f32x4){0.f, 0.f, 0.f, 0.f};

  #pragma unroll
  for (int kk = 0; kk < 4; ++kk) {
    int acol = (kk * 4 + kq) ^ (ar & 7);
    short8 a = *(const short8*)&A4[(ar << 4) | acol];
    #pragma unroll
    for (int jt = 0; jt < 4; ++jt) {
      int br = jt * 16 + l15;
      int bcol = (kk * 4 + kq) ^ (br & 7);
      short8 bf = *(const short8*)&B4[(br << 4) | bcol];
      acc[jt] = __builtin_amdgcn_mfma_f32_16x16x32_bf16(a, bf, acc[jt], 0, 0, 0);
    }
  }

  unsigned short* Dc = Dmat + ((size_t)cloud << 20);
  unsigned long long* bestc = best + cloud * NPTS;

  unsigned k1[4] = {0xFFFFFFFFu, 0xFFFFFFFFu, 0xFFFFFFFFu, 0xFFFFFFFFu};
  unsigned k2[4] = {0xFFFFFFFFu, 0xFFFFFFFFu, 0xFFFFFFFFu, 0xFFFFFFFFu};

  #pragma unroll
  for (int jt = 0; jt < 4; ++jt) {
    int jl = jt * 16 + l15;
    int gj = j0 + jl;
    float sqj = sqj_sh[jl];
    #pragma unroll
    for (int r = 0; r < 4; ++r) {
      int il = w * 16 + kq * 4 + r;
      int gi = i0 + il;
      float d2 = sqi_sh[il] + sqj - 2.f * acc[jt][r];
      float d = sqrtf(fmaxf(d2, 0.f) + 1e-12f);
      unsigned h = (gi == gj) ? 0x7C00u : (unsigned)__half_as_ushort(__float2half(d));
      Dc[(size_t)gi * NPTS + gj] = (unsigned short)h;
      unsigned key = (h << 16) | (unsigned)gj;
      if (key < k1[r]) { k2[r] = k1[r]; k1[r] = key; }
      else if (key < k2[r]) k2[r] = key;
    }
  }

  // merge top-2 pairs across the 16-lane col group
  #pragma unroll
  for (int mask = 1; mask < 16; mask <<= 1) {
    #pragma unroll
    for (int r = 0; r < 4; ++r) {
      unsigned o1 = __shfl_xor(k1[r], mask);
      unsigned o2 = __shfl_xor(k2[r], mask);
      unsigned n1 = umin32(k1[r], o1);
      unsigned n2 = umin32(umax32(k1[r], o1), umin32(k2[r], o2));
      k1[r] = n1; k2[r] = n2;
    }
  }

  if (l15 == 0) {
    #pragma unroll
    for (int r = 0; r < 4; ++r) {
      unsigned gi = (unsigned)(i0 + w * 16 + kq * 4 + r);
      // stripe-major layout for coalesced solve-side loads
      cand[(((size_t)(cloud * 16 + blockIdx.x)) << 10) + gi] = make_uint2(k1[r], k2[r]);
      unsigned j = k1[r] & 0xFFFFu, hv = k1[r] >> 16;
      unsigned cmn = umin32(gi, j);
      unsigned cmx = gi + j - cmn;
      unsigned long long k64 =
          ((unsigned long long)hv << 20) | (unsigned long long)((cmn << 10) | cmx);
      atomicMin(&bestc[gi], k64);
    }
  }
}

// ---------------- single-block-per-cloud Boruvka solve + fused sort ----------------
// 1024 threads; all cross-round state in LDS. Thread tid owns row tid.
__global__ __launch_bounds__(1024) void boruvka_solve(const unsigned short* __restrict__ Dmat,
                                                      const uint2* __restrict__ cand,
                                                      const unsigned long long* __restrict__ best_init,
                                                      float* __restrict__ deaths_out) {
  const int cloud = blockIdx.x;
  const int tid = threadIdx.x;
  const int lane = tid & 63, wid = tid >> 6;

  __shared__ unsigned short comp16[NPTS];
  __shared__ unsigned short par[NPTS];
  __shared__ unsigned long long best64[NPTS];
  __shared__ float dl[NPTS];
  __shared__ unsigned short fb[NPTS];
  __shared__ unsigned nfb_sh, dcnt_sh, cnt_sh;

  // reg-cache this row's 16 candidate pairs (coalesced stripe-major loads)
  uint2 c[16];
  const uint2* candc = cand + ((size_t)cloud << 14);
  #pragma unroll
  for (int s = 0; s < 16; ++s) c[s] = candc[(s << 10) + tid];

  comp16[tid] = (unsigned short)tid;
  par[tid] = (unsigned short)tid;
  best64[tid] = best_init[cloud * NPTS + tid];
  dl[tid] = BIGF;
  if (tid == 0) { dcnt_sh = 0; nfb_sh = 0; }
  __syncthreads();

  const uint4* p = (const uint4*)(Dmat + ((size_t)cloud << 20));
  const unsigned jb0 = (unsigned)(lane << 3), jb1 = 512u + jb0;

  for (int rnd = 0; rnd < 11; ++rnd) {
    if (rnd > 0) {
      // ---- candidate phase: thread tid = row tid ----
      unsigned ci = comp16[tid];
      unsigned e = 0xFFFFFFFFu;
      unsigned bw = 0xFFFFu;
      #pragma unroll
      for (int s = 0; s < 16; ++s) {
        unsigned j1 = c[s].x & 0xFFFFu, j2 = c[s].y & 0xFFFFu;
        bool o1 = ((unsigned)comp16[j1] != ci);
        bool o2 = ((unsigned)comp16[j2] != ci);
        unsigned es = o1 ? c[s].x : (o2 ? c[s].y : 0xFFFFFFFFu);
        unsigned bs = (!o1 && !o2) ? (c[s].y >> 16) : 0xFFFFu;
        e = umin32(e, es);
        bw = umin32(bw, bs);
      }
      if ((e >> 16) < bw) {  // certificate: hidden edges strictly heavier
        if (e != 0xFFFFFFFFu) {
          unsigned j = e & 0xFFFFu, hv = e >> 16;
          unsigned cmn = umin32((unsigned)tid, j);
          unsigned cmx = (unsigned)tid + j - cmn;
          unsigned long long k64 =
              ((unsigned long long)hv << 20) | (unsigned long long)((cmn << 10) | cmx);
          atomicMin(&best64[ci], k64);
        }
      } else {
        unsigned slot = atomicAdd(&nfb_sh, 1u);
        fb[slot] = (unsigned short)tid;
      }
      __syncthreads();

      // ---- fallback: wave-parallel exact full-row rescan ----
      unsigned nfb = nfb_sh;
      if (nfb) {
        unsigned cj[16];
        #pragma unroll
        for (int q = 0; q < 8; ++q) cj[q] = comp16[jb0 + q];
        #pragma unroll
        for (int q = 0; q < 8; ++q) cj[8 + q] = comp16[jb1 + q];
        for (unsigned k = (unsigned)wid; k < nfb; k += 16) {
          int frow = fb[k];
          unsigned fci = (unsigned)comp16[frow];
          uint4 ra = p[frow * 128 + lane];
          uint4 rb = p[frow * 128 + 64 + lane];
          unsigned key = 0xFFFFFFFFu;
          #define ENT(word, cl, ch, jb) { \
            unsigned klo = ((word) << 16) | (jb); \
            unsigned khi = ((word) & 0xFFFF0000u) | ((jb) + 1); \
            key = umin32(key, (cl) == fci ? 0xFFFFFFFFu : klo); \
            key = umin32(key, (ch) == fci ? 0xFFFFFFFFu : khi); }
          ENT(ra.x, cj[0],  cj[1],  jb0 + 0) ENT(ra.y, cj[2],  cj[3],  jb0 + 2)
          ENT(ra.z, cj[4],  cj[5],  jb0 + 4) ENT(ra.w, cj[6],  cj[7],  jb0 + 6)
          ENT(rb.x, cj[8],  cj[9],  jb1 + 0) ENT(rb.y, cj[10], cj[11], jb1 + 2)
          ENT(rb.z, cj[12], cj[13], jb1 + 4) ENT(rb.w, cj[14], cj[15], jb1 + 6)
          #undef ENT
          #define DPPMIN(ctrl) { \
            unsigned tv = (unsigned)__builtin_amdgcn_update_dpp((int)key, (int)key, (ctrl), 0xF, 0xF, false); \
            key = umin32(key, tv); }
          DPPMIN(0x111) DPPMIN(0x112) DPPMIN(0x114) DPPMIN(0x118)
          DPPMIN(0x142) DPPMIN(0x143)
          #undef DPPMIN
          if (lane == 63 && key != 0xFFFFFFFFu) {
            unsigned wv = key >> 16, v = key & 0xFFFFu;
            unsigned cmn = umin32((unsigned)frow, v);
            unsigned cmx = (unsigned)frow + v - cmn;
            unsigned long long k64 =
                ((unsigned long long)wv << 20) | (unsigned long long)((cmn << 10) | cmx);
            atomicMin(&best64[fci], k64);
          }
        }
      }
      __syncthreads();
    }

    // ---- merge: hook, 2-cycle break, append, root-chase ----
    unsigned long long bk = best64[tid];
    unsigned cold = comp16[tid];
    unsigned partner = (unsigned)tid;
    unsigned wb = 0;
    if (cold == (unsigned)tid && bk != BMAX) {
      wb = (unsigned)(bk >> 20) & 0xFFFFu;
      unsigned cmin = (unsigned)(bk >> 10) & 1023u;
      unsigned cmax = (unsigned)bk & 1023u;
      unsigned ca = comp16[cmin], cb = comp16[cmax];
      partner = (ca == (unsigned)tid) ? cb : ca;
      par[tid] = (unsigned short)partner;
    }
    __syncthreads();
    unsigned pp = par[partner];
    bool twoc = (partner != (unsigned)tid) && (pp == (unsigned)tid);
    bool winner = twoc && ((unsigned)tid < partner);
    bool append = (partner != (unsigned)tid) && !winner;
    __syncthreads();
    if (winner) par[tid] = (unsigned short)tid;
    if (append) {
      unsigned slot = atomicAdd(&dcnt_sh, 1u);
      dl[slot] = __half2float(__ushort_as_half((unsigned short)wb));
    }
    __syncthreads();
    // chase to root (par static; no barriers needed during chase)
    unsigned x = cold;
    unsigned px = par[x];
    while (px != x) { x = px; px = par[x]; }
    __syncthreads();
    comp16[tid] = (unsigned short)x;
    best64[tid] = BMAX;
    par[tid] = (unsigned short)tid;
    if (tid == 0) { cnt_sh = 0; nfb_sh = 0; }
    __syncthreads();
    unsigned long long bl = __ballot(x == (unsigned)tid);
    if (lane == 0) atomicAdd(&cnt_sh, (unsigned)__popcll(bl));
    __syncthreads();
    if (cnt_sh == 1u) break;
  }

  // ---- fused bitonic sort of dl[1024] (dl[1023] == BIGF pad) ----
  for (int k = 2; k <= NPTS; k <<= 1) {
    for (int jj = k >> 1; jj > 0; jj >>= 1) {
      int i = tid;
      int l = i ^ jj;
      if (l > i) {
        float va = dl[i], vb = dl[l];
        bool up = ((i & k) == 0);
        if ((va > vb) == up) { dl[i] = vb; dl[l] = va; }
      }
      __syncthreads();
    }
  }
  deaths_out[(size_t)cloud * NPTS + tid] = dl[tid];
}

// ---------------- fallback MSE kernel (small ws path) ----------------
__global__ __launch_bounds__(256) void mse_kernel(const float* __restrict__ a,
                                                  const float* __restrict__ b,
                                                  double* __restrict__ acc, int n4) {
  int i = blockIdx.x * blockDim.x + threadIdx.x;
  int stride = gridDim.x * blockDim.x;
  const float4* a4 = (const float4*)a;
  const float4* b4 = (const float4*)b;
  float s = 0.f;
  for (int k = i; k < n4; k += stride) {
    float4 va = a4[k], vb = b4[k];
    float dx = va.x - vb.x, dy = va.y - vb.y, dz = va.z - vb.z, dw = va.w - vb.w;
    s += dx * dx + dy * dy + dz * dz + dw * dw;
  }
  #pragma unroll
  for (int off = 32; off; off >>= 1) s += __shfl_xor(s, off);
  __shared__ float wsum[4];
  int lane = threadIdx.x & 63, wid = threadIdx.x >> 6;
  if (lane == 0) wsum[wid] = s;
  __syncthreads();
  if (threadIdx.x == 0)
    atomicAdd(acc, (double)(wsum[0] + wsum[1] + wsum[2] + wsum[3]));
}

// ---------------- fallback: fused Prim+sort from x (small ws) ----------------
__global__ __launch_bounds__(1024) void prim_kernel(const float* __restrict__ x1,
                                                    const float* __restrict__ x2,
                                                    float* __restrict__ sorted_out) {
  const int cloud = blockIdx.x;
  const int b = cloud & (BATCH - 1);
  const int src = cloud >> 4;
  const float* xbase = (src ? x2 : x1) + (size_t)b * NPTS * DIM;
  const int j = threadIdx.x;

  __shared__ float xi_sh[DIM];
  __shared__ float sq_sh[NPTS];
  __shared__ float redw[16];
  __shared__ int   redi[16];
  __shared__ float deaths[NPTS];

  const float4* xr = (const float4*)(xbase + (size_t)j * DIM);
  {
    float ax = 0.f, ay = 0.f, az = 0.f, aw = 0.f;
    #pragma unroll 8
    for (int m = 0; m < DIM / 4; ++m) {
      float4 v = xr[m];
      ax = fmaf(v.x, v.x, ax); ay = fmaf(v.y, v.y, ay);
      az = fmaf(v.z, v.z, az); aw = fmaf(v.w, v.w, aw);
    }
    sq_sh[j] = (ax + ay) + (az + aw);
  }
  const float sqj = sq_sh[j];

  float mind = BIGF;
  bool in_tree = (j == 0);
  int  cur = 0;

  for (int t = 0; t < NPTS - 1; ++t) {
    if (threadIdx.x < DIM / 4)
      ((float4*)xi_sh)[threadIdx.x] = ((const float4*)(xbase + (size_t)cur * DIM))[threadIdx.x];
    __syncthreads();

    const float4* xi4 = (const float4*)xi_sh;
    float ax = 0.f, ay = 0.f, az = 0.f, aw = 0.f;
    #pragma unroll 8
    for (int m = 0; m < DIM / 4; ++m) {
      float4 v = xr[m];
      float4 u = xi4[m];
      ax = fmaf(v.x, u.x, ax); ay = fmaf(v.y, u.y, ay);
      az = fmaf(v.z, u.z, az); aw = fmaf(v.w, u.w, aw);
    }
    float dot = (ax + ay) + (az + aw);
    float d2 = sq_sh[cur] + sqj - 2.f * dot;
    float d = sqrtf(fmaxf(d2, 0.f) + 1e-12f);
    mind = in_tree ? BIGF : fminf(mind, d);

    float w = mind;
    int idx = j;
    #pragma unroll
    for (int off = 32; off; off >>= 1) {
      float w2 = __shfl_xor(w, off);
      int i2 = __shfl_xor(idx, off);
      if (w2 < w || (w2 == w && i2 < idx)) { w = w2; idx = i2; }
    }
    int lane = j & 63, wid = j >> 6;
    if (lane == 0) { redw[wid] = w; redi[wid] = idx; }
    __syncthreads();

    float cw = redw[0];
    int ci = redi[0];
    #pragma unroll
    for (int q = 1; q < 16; ++q) {
      float w2 = redw[q]; int i2 = redi[q];
      if (w2 < cw || (w2 == cw && i2 < ci)) { cw = w2; ci = i2; }
    }
    if (j == ci) in_tree = true;
    if (j == 0)  deaths[t] = cw;
    cur = ci;
  }

  if (threadIdx.x == 0) deaths[NPTS - 1] = BIGF;
  __syncthreads();

  for (int k = 2; k <= NPTS; k <<= 1) {
    for (int jj = k >> 1; jj > 0; jj >>= 1) {
      int i = threadIdx.x;
      int l = i ^ jj;
      if (l > i) {
        float va = deaths[i], vb = deaths[l];
        bool up = ((i & k) == 0);
        if ((va > vb) == up) { deaths[i] = vb; deaths[l] = va; }
      }
      __syncthreads();
    }
  }
  sorted_out[(size_t)cloud * NPTS + threadIdx.x] = deaths[threadIdx.x];
}

// ---------------- final combine ----------------
__global__ __launch_bounds__(1024) void final_kernel(const double* __restrict__ mse_acc,
                                                     const float* __restrict__ sorted,
                                                     float* __restrict__ out) {
  int wid = threadIdx.x >> 6;
  int lane = threadIdx.x & 63;
  const float* s1 = sorted + (size_t)wid * NPTS;
  const float* s2 = sorted + (size_t)(BATCH + wid) * NPTS;
  float s = 0.f;
  for (int k = lane; k < NPTS; k += 64) {
    float dlt = s1[k] - s2[k];
    s += dlt * dlt;
  }
  #pragma unroll
  for (int off = 32; off; off >>= 1) s += __shfl_xor(s, off);
  __shared__ float part[16];
  if (lane == 0) part[wid] = sqrtf(s);
  __syncthreads();
  if (threadIdx.x == 0) {
    float topo = 0.f;
    #pragma unroll
    for (int q = 0; q < 16; ++q) topo += part[q];
    float mse = (float)(mse_acc[0] / (double)((size_t)BATCH * NPTS * DIM));
    out[0] = 1.0f * mse + 0.1f * topo;
  }
}

extern "C" void kernel_launch(void* const* d_in, const int* in_sizes, int n_in,
                              void* d_out, int out_size, void* d_ws, size_t ws_size,
                              hipStream_t stream) {
  const float* x1 = (const float*)d_in[0];
  const float* x2 = (const float*)d_in[1];
  double* mse_acc = (double*)d_ws;
  float* deaths   = (float*)((char*)d_ws + DEATHS_OFF);
  float* out      = (float*)d_out;

  hipMemsetAsync(d_ws, 0, 64, stream);

  if (ws_size >= WS_NEED) {
    unsigned short* Dmat = (unsigned short*)((char*)d_ws + D_OFF);
    unsigned short* xbf  = (unsigned short*)((char*)d_ws + XBF_OFF);
    float* sqg           = (float*)((char*)d_ws + SQ_OFF);
    unsigned long long* best = (unsigned long long*)((char*)d_ws + BEST_OFF);
    uint2* cand          = (uint2*)((char*)d_ws + CAND_OFF);

    prep_mse<<<dim3(BATCH, 8), 256, 0, stream>>>(x1, x2, xbf, sqg, best, mse_acc);
    distmat_mfma<<<dim3(16, 16, NCLOUD), 256, 0, stream>>>(xbf, sqg, Dmat, best, cand);
    boruvka_solve<<<NCLOUD, 1024, 0, stream>>>(Dmat, cand, best, deaths);
  } else {
    int n4 = (BATCH * NPTS * DIM) / 4;
    mse_kernel<<<1024, 256, 0, stream>>>(x1, x2, mse_acc, n4);
    prim_kernel<<<NCLOUD, 1024, 0, stream>>>(x1, x2, deaths);
  }

  final_kernel<<<1, 1024, 0, stream>>>(mse_acc, deaths, out);
}